// Round 1
// baseline (887.041 us; speedup 1.0000x reference)
//
#include <hip/hip_runtime.h>

// Classwise ECE: probs [N=100000, C=1000] f32, labels [N] int32 -> scalar f32.
// Strategy: class-tiled per-thread-private LDS histograms, packed
// (count<<24 | conf_fixed_q16) so each element costs ONE ds_add_u32.
// Global accumulation via integer/u64 atomics (deterministic), then a tiny
// reduce kernel computes sum_b |avg_conf - acc| * count/N per class, /C.

#define NBINS 15
#define TC    128   // classes per block
#define RPC   250   // rows per chunk (count field must stay < 256)

__global__ __launch_bounds__(TC) void ece_hist(
    const float* __restrict__ probs, const int* __restrict__ labels,
    int N, int C,
    unsigned long long* __restrict__ g_conf,  // [C*NBINS] fixed-point q16 sums
    unsigned* __restrict__ g_cnt,             // [C*NBINS]
    unsigned* __restrict__ g_cor)             // [C*NBINS]
{
    __shared__ unsigned sA[TC * NBINS];  // count<<24 | conf_fixed (q16)
    __shared__ unsigned sB[TC * NBINS];  // correct counts

    const int t = threadIdx.x;
    for (int i = t; i < TC * NBINS; i += TC) { sA[i] = 0u; sB[i] = 0u; }
    __syncthreads();

    const int chunk = blockIdx.x;
    const int tile  = blockIdx.y;
    const int cls   = tile * TC + t;
    const bool cok  = (cls < C);
    const int col   = cok ? cls : 0;

    const int r0   = chunk * RPC;
    const int rend = (N - r0 < RPC) ? (N - r0) : RPC;
    const float* p = probs + (size_t)r0 * C + col;

    unsigned* myA = sA + t * NBINS;
    unsigned* myB = sB + t * NBINS;

    #pragma unroll 4
    for (int r = 0; r < rend; ++r) {
        float v = p[(size_t)r * C];
        int lab = labels[r0 + r];          // uniform across block -> s_load
        int bin = (int)ceilf(v * 15.0f) - 1;
        bin = bin > (NBINS - 1) ? (NBINS - 1) : bin;
        const bool valid = (v > 0.0f) && cok;
        const int b = bin < 0 ? 0 : bin;
        unsigned inc = valid ? ((1u << 24) | (unsigned)(v * 65536.0f)) : 0u;
        atomicAdd(&myA[b], inc);           // ds_add_u32, private slot
        if (valid && lab == cls) atomicAdd(&myB[b], 1u);
    }
    __syncthreads();

    if (cok) {
        for (int b = 0; b < NBINS; ++b) {
            unsigned a   = myA[b];
            unsigned cnt = a >> 24;
            unsigned cf  = a & 0xFFFFFFu;
            unsigned cr  = myB[b];
            int slot = cls * NBINS + b;
            if (cnt) {
                atomicAdd(&g_cnt[slot], cnt);
                atomicAdd(&g_conf[slot], (unsigned long long)cf);
            }
            if (cr) atomicAdd(&g_cor[slot], cr);
        }
    }
}

__global__ __launch_bounds__(256) void ece_final(
    const unsigned long long* __restrict__ g_conf,
    const unsigned* __restrict__ g_cnt,
    const unsigned* __restrict__ g_cor,
    int N, int C, float* __restrict__ out)
{
    float local = 0.0f;
    const int total = C * NBINS;
    for (int i = threadIdx.x; i < total; i += 256) {
        unsigned cnt = g_cnt[i];
        if (cnt) {
            float denom = (float)cnt;
            float conf  = (float)g_conf[i] * (1.0f / 65536.0f);
            float acc   = (float)g_cor[i] / denom;
            float avg   = conf / denom;
            local += fabsf(avg - acc) * (denom / (float)N);
        }
    }
    for (int o = 32; o; o >>= 1) local += __shfl_down(local, o);
    __shared__ float ws[4];
    const int wid = threadIdx.x >> 6, lane = threadIdx.x & 63;
    if (lane == 0) ws[wid] = local;
    __syncthreads();
    if (threadIdx.x == 0) {
        out[0] = (ws[0] + ws[1] + ws[2] + ws[3]) / (float)C;
    }
}

extern "C" void kernel_launch(void* const* d_in, const int* in_sizes, int n_in,
                              void* d_out, int out_size, void* d_ws, size_t ws_size,
                              hipStream_t stream) {
    const float* probs = (const float*)d_in[0];
    const int*   labels = (const int*)d_in[1];
    const int N = in_sizes[1];              // 100000
    const int C = in_sizes[0] / N;          // 1000

    const int slots = C * NBINS;            // 15000
    unsigned long long* g_conf = (unsigned long long*)d_ws;              // 8B * slots
    unsigned* g_cnt = (unsigned*)((char*)d_ws + (size_t)slots * 8);      // 4B * slots
    unsigned* g_cor = (unsigned*)((char*)d_ws + (size_t)slots * 12);     // 4B * slots
    const size_t ws_bytes = (size_t)slots * 16;

    hipMemsetAsync(d_ws, 0, ws_bytes, stream);

    const int nchunks = (N + RPC - 1) / RPC;    // 400
    const int ntiles  = (C + TC - 1) / TC;      // 8
    dim3 grid(nchunks, ntiles);
    ece_hist<<<grid, TC, 0, stream>>>(probs, labels, N, C, g_conf, g_cnt, g_cor);
    ece_final<<<1, 256, 0, stream>>>(g_conf, g_cnt, g_cor, N, C, (float*)d_out);
}

// Round 2
// 298.757 us; speedup vs baseline: 2.9691x; 2.9691x over previous
//
#include <hip/hip_runtime.h>

// Classwise ECE, probs [N=100000, C=1000] f32, labels [N] i32 -> scalar f32.
// R2: no global atomics in the hot path. Per-thread-private LDS slots packed
// (count<<32 | conf_q16) -> one ds_add_u64 per element; per-chunk partials
// flushed with plain coalesced stores; small reduce kernels finish.

#define NBINS   15
#define TC      256          // classes per block tile
#define THREADS 128          // 2 classes per thread (float2 loads)
#define SLOTS_PER_TILE (TC * NBINS)   // 3840

__global__ __launch_bounds__(THREADS) void ece_hist(
    const float* __restrict__ probs, int N, int C, int R, int tiles,
    unsigned long long* __restrict__ partial)   // [chunk][tiles*SLOTS_PER_TILE]
{
    __shared__ unsigned long long sA[SLOTS_PER_TILE];
    const int t = threadIdx.x;
    for (int i = t; i < SLOTS_PER_TILE; i += THREADS) sA[i] = 0ull;
    __syncthreads();

    const int chunk = blockIdx.x;
    const int tile  = blockIdx.y;
    const int cls0  = tile * TC + t * 2;
    // Clamp load column for dead classes (>= C); their LDS slots map to
    // partial slots >= C*NBINS which the reduce kernel never reads.
    const int col   = (cls0 <= C - 2) ? cls0 : (C - 2);

    const int r0   = chunk * R;
    const int rend = (N - r0 < R) ? (N - r0) : R;
    const float2* p = (const float2*)(probs + (size_t)r0 * C + col);
    const size_t rowstep = (size_t)(C >> 1);

    unsigned long long* s0 = sA + (size_t)(2 * t) * NBINS;
    unsigned long long* s1 = s0 + NBINS;

    #pragma unroll 8
    for (int r = 0; r < rend; ++r) {
        float2 v = p[(size_t)r * rowstep];

        int b0 = (int)(v.x * 15.0f);               // trunc == floor (v>=0)
        b0 = b0 < NBINS - 1 ? b0 : NBINS - 1;
        unsigned c0 = (unsigned)fmaf(v.x, 65536.0f, 0.5f);
        unsigned long long inc0 = (v.x > 0.0f) ? ((1ull << 32) | c0) : 0ull;
        atomicAdd(&s0[b0], inc0);                  // ds_add_u64, private slot

        int b1 = (int)(v.y * 15.0f);
        b1 = b1 < NBINS - 1 ? b1 : NBINS - 1;
        unsigned c1 = (unsigned)fmaf(v.y, 65536.0f, 0.5f);
        unsigned long long inc1 = (v.y > 0.0f) ? ((1ull << 32) | c1) : 0ull;
        atomicAdd(&s1[b1], inc1);
    }
    __syncthreads();

    unsigned long long* dst = partial
        + (size_t)chunk * ((size_t)tiles * SLOTS_PER_TILE)
        + (size_t)tile * SLOTS_PER_TILE;
    for (int i = t; i < SLOTS_PER_TILE; i += THREADS) dst[i] = sA[i];
}

// One gather per sample: bump correct-count for (label, bin(conf_label)).
__global__ __launch_bounds__(256) void ece_cor(
    const float* __restrict__ probs, const int* __restrict__ labels,
    int N, int C, unsigned* __restrict__ g_cor)
{
    int n = blockIdx.x * 256 + threadIdx.x;
    if (n >= N) return;
    int lab = labels[n];
    if (lab < 0 || lab >= C) return;
    float v = probs[(size_t)n * C + lab];
    if (v <= 0.0f) return;                          // dump bin: excluded
    int b = (int)(v * 15.0f);
    b = b < NBINS - 1 ? b : NBINS - 1;
    atomicAdd(&g_cor[lab * NBINS + b], 1u);
}

// contrib = |avg_conf - acc| * cnt/N = |conf_sum - cor| / N  (cnt cancels)
__global__ __launch_bounds__(256) void ece_reduce(
    const unsigned long long* __restrict__ partial,
    const unsigned* __restrict__ g_cor,
    int chunks, int slabStride, int C, int N,
    unsigned long long* __restrict__ accum)
{
    int i = blockIdx.x * 256 + threadIdx.x;
    float contrib = 0.0f;
    if (i < C * NBINS) {
        unsigned long long cntS = 0ull, confS = 0ull;
        for (int k = 0; k < chunks; ++k) {
            unsigned long long x = partial[(size_t)k * slabStride + i];
            cntS  += x >> 32;
            confS += x & 0xFFFFFFFFull;
        }
        if (cntS) {
            float conf = (float)confS * (1.0f / 65536.0f);
            float cor  = (float)g_cor[i];
            contrib = fabsf(conf - cor) * (1.0f / (float)N);
        }
    }
    for (int o = 32; o; o >>= 1) contrib += __shfl_down(contrib, o);
    __shared__ float ws[4];
    const int wid = threadIdx.x >> 6, lane = threadIdx.x & 63;
    if (lane == 0) ws[wid] = contrib;
    __syncthreads();
    if (threadIdx.x == 0) {
        float s = ws[0] + ws[1] + ws[2] + ws[3];
        // fixed-point q40 -> deterministic accumulation
        atomicAdd(accum, (unsigned long long)(s * 1099511627776.0f));
    }
}

__global__ void ece_fin(const unsigned long long* __restrict__ accum,
                        int C, float* __restrict__ out)
{
    out[0] = (float)((double)accum[0] * (1.0 / 1099511627776.0) / (double)C);
}

extern "C" void kernel_launch(void* const* d_in, const int* in_sizes, int n_in,
                              void* d_out, int out_size, void* d_ws, size_t ws_size,
                              hipStream_t stream) {
    const float* probs  = (const float*)d_in[0];
    const int*   labels = (const int*)d_in[1];
    const int N = in_sizes[1];              // 100000
    const int C = in_sizes[0] / N;          // 1000

    const int tiles = (C + TC - 1) / TC;    // 4
    const int slabStride = tiles * SLOTS_PER_TILE;       // 15360 slots
    const size_t slabBytes = (size_t)slabStride * 8;     // 122880 B
    const size_t headBytes = 65536;         // accum(8B) + g_cor(61440B), padded

    // ws layout: [accum u64][g_cor u32 x slabStride]...[partials]
    unsigned long long* accum = (unsigned long long*)d_ws;
    unsigned* g_cor = (unsigned*)((char*)d_ws + 8);
    unsigned long long* partial = (unsigned long long*)((char*)d_ws + headBytes);

    int chunksMax = (ws_size > headBytes + 2 * slabBytes)
                  ? (int)((ws_size - headBytes) / slabBytes) : 2;
    int chunks = chunksMax < 250 ? chunksMax : 250;
    if (chunks < 2) chunks = 2;             // R <= 65535 keeps q16 sum in u32
    const int R = (N + chunks - 1) / chunks;

    hipMemsetAsync(d_ws, 0, headBytes, stream);

    dim3 hgrid(chunks, tiles);
    ece_hist<<<hgrid, THREADS, 0, stream>>>(probs, N, C, R, tiles, partial);
    ece_cor<<<(N + 255) / 256, 256, 0, stream>>>(probs, labels, N, C, g_cor);
    ece_reduce<<<(C * NBINS + 255) / 256, 256, 0, stream>>>(
        partial, g_cor, chunks, slabStride, C, N, accum);
    ece_fin<<<1, 1, 0, stream>>>(accum, C, (float*)d_out);
}

// Round 3
// 148.102 us; speedup vs baseline: 5.9894x; 2.0172x over previous
//
#include <hip/hip_runtime.h>

// Classwise ECE, probs [N=100000, C=1000] f32, labels [N] i32 -> scalar f32.
// R3: u32 LDS slots (count<<24 | conf_q16, R<=255 rows/chunk), 20 waves/CU,
// 1280 hist blocks; plain-store partials; two-stage deterministic reduce.

#define NBINS   15
#define TC      512                 // classes per tile
#define THREADS 256                 // 2 classes per thread (float2)
#define SLOTS   (TC * NBINS)        // 7680 u32 = 30720 B LDS
#define TILES   2                   // covers C <= 1024
#define SLAB    (TILES * SLOTS)     // 15360 u32 per chunk
#define NGROUP  16                  // stage-1 chunk groups

__global__ __launch_bounds__(THREADS, 5) void ece_hist(
    const float* __restrict__ probs, int N, int C, int R,
    unsigned* __restrict__ partial)          // [chunks][SLAB]
{
    __shared__ unsigned sA[SLOTS];
    const int t = threadIdx.x;
    #pragma unroll
    for (int i = t; i < SLOTS; i += THREADS) sA[i] = 0u;
    __syncthreads();

    const int chunk = blockIdx.x;
    const int tile  = blockIdx.y;
    const int cls0  = tile * TC + 2 * t;
    const int col   = (cls0 <= C - 2) ? cls0 : (C - 2);  // dead classes ignored later

    const int r0 = chunk * R;
    int rend = N - r0; if (rend > R) rend = R;

    const float2* p = (const float2*)(probs + (size_t)r0 * C + col);
    const size_t rowstep = (size_t)(C >> 1);
    unsigned* s0 = sA + (2 * t) * NBINS;
    unsigned* s1 = s0 + NBINS;

    #pragma unroll 8
    for (int r = 0; r < rend; ++r) {
        float2 v = p[(size_t)r * rowstep];

        int b0 = (int)(v.x * 15.0f);            // trunc == floor (v>=0)
        b0 = b0 < NBINS - 1 ? b0 : NBINS - 1;
        unsigned c0 = (unsigned)fmaf(v.x, 65536.0f, 0.5f);
        unsigned inc0 = (v.x > 0.0f) ? ((1u << 24) | c0) : 0u;
        atomicAdd(&s0[b0], inc0);               // ds_add_u32, private slot

        int b1 = (int)(v.y * 15.0f);
        b1 = b1 < NBINS - 1 ? b1 : NBINS - 1;
        unsigned c1 = (unsigned)fmaf(v.y, 65536.0f, 0.5f);
        unsigned inc1 = (v.y > 0.0f) ? ((1u << 24) | c1) : 0u;
        atomicAdd(&s1[b1], inc1);
    }
    __syncthreads();

    unsigned* dst = partial + (size_t)chunk * SLAB + (size_t)tile * SLOTS;
    #pragma unroll
    for (int i = t; i < SLOTS; i += THREADS) dst[i] = sA[i];
}

// One gather per sample: correct-count for (label, bin(conf_label)).
__global__ __launch_bounds__(256) void ece_cor(
    const float* __restrict__ probs, const int* __restrict__ labels,
    int N, int C, unsigned* __restrict__ g_cor)
{
    int n = blockIdx.x * 256 + threadIdx.x;
    if (n >= N) return;
    int lab = labels[n];
    if (lab < 0 || lab >= C) return;
    float v = probs[(size_t)n * C + lab];
    if (v <= 0.0f) return;
    int b = (int)(v * 15.0f);
    b = b < NBINS - 1 ? b : NBINS - 1;
    atomicAdd(&g_cor[lab * NBINS + b], 1u);
}

// Stage 1: per chunk-group partial sums (unpack count/conf).
__global__ __launch_bounds__(256) void ece_red1(
    const unsigned* __restrict__ partial, int chunks, int gsz,
    uint2* __restrict__ stage1)              // [NGROUP][SLAB]
{
    int i = blockIdx.x * 256 + threadIdx.x;
    if (i >= SLAB) return;
    int g = blockIdx.y;
    int k0 = g * gsz;
    int k1 = k0 + gsz; if (k1 > chunks) k1 = chunks;
    unsigned cnt = 0, conf = 0;
    #pragma unroll 8
    for (int k = k0; k < k1; ++k) {
        unsigned x = partial[(size_t)k * SLAB + i];
        cnt  += x >> 24;
        conf += x & 0xFFFFFFu;
    }
    stage1[(size_t)g * SLAB + i] = make_uint2(cnt, conf);
}

// Stage 2: contrib = |avg_conf - acc| * cnt/N = |conf_sum - cor|/N (cnt cancels)
__global__ __launch_bounds__(256) void ece_red2(
    const uint2* __restrict__ stage1, const unsigned* __restrict__ g_cor,
    int C, int N, unsigned long long* __restrict__ accum)
{
    int i = blockIdx.x * 256 + threadIdx.x;
    float contrib = 0.0f;
    if (i < C * NBINS) {
        unsigned cnt = 0; unsigned long long conf = 0;
        #pragma unroll
        for (int g = 0; g < NGROUP; ++g) {
            uint2 x = stage1[(size_t)g * SLAB + i];
            cnt += x.x; conf += x.y;
        }
        if (cnt) {
            float cf = (float)conf * (1.0f / 65536.0f);
            contrib = fabsf(cf - (float)g_cor[i]) * (1.0f / (float)N);
        }
    }
    for (int o = 32; o; o >>= 1) contrib += __shfl_down(contrib, o);
    __shared__ float ws[4];
    const int wid = threadIdx.x >> 6, lane = threadIdx.x & 63;
    if (lane == 0) ws[wid] = contrib;
    __syncthreads();
    if (threadIdx.x == 0) {
        float s = ws[0] + ws[1] + ws[2] + ws[3];
        atomicAdd(accum, (unsigned long long)(s * 1099511627776.0f)); // q40
    }
}

__global__ void ece_fin(const unsigned long long* __restrict__ accum,
                        int C, float* __restrict__ out)
{
    out[0] = (float)((double)accum[0] * (1.0 / 1099511627776.0) / (double)C);
}

extern "C" void kernel_launch(void* const* d_in, const int* in_sizes, int n_in,
                              void* d_out, int out_size, void* d_ws, size_t ws_size,
                              hipStream_t stream) {
    const float* probs  = (const float*)d_in[0];
    const int*   labels = (const int*)d_in[1];
    const int N = in_sizes[1];              // 100000
    const int C = in_sizes[0] / N;          // 1000

    // ws layout: [accum u64][g_cor u32 x SLAB] pad to 64K | stage1 | partials
    const size_t headBytes   = 65536;
    const size_t stage1Bytes = (size_t)NGROUP * SLAB * sizeof(uint2);  // ~1.97 MB
    const size_t off_partial = headBytes + stage1Bytes;
    const size_t slabBytes   = (size_t)SLAB * 4;                       // 61440

    unsigned long long* accum  = (unsigned long long*)d_ws;
    unsigned*           g_cor  = (unsigned*)((char*)d_ws + 8);
    uint2*              stage1 = (uint2*)((char*)d_ws + headBytes);
    unsigned*           partial = (unsigned*)((char*)d_ws + off_partial);

    long long avail = (long long)ws_size - (long long)off_partial;
    int chunks = (int)(avail / (long long)slabBytes);
    if (chunks > 640) chunks = 640;         // 640x2 tiles = 1280 blocks = 5/CU
    if (chunks < 393) chunks = 393;         // keeps R<=255 (count/conf fields)
    const int R = (N + chunks - 1) / chunks;
    const int gsz = (chunks + NGROUP - 1) / NGROUP;

    hipMemsetAsync(d_ws, 0, headBytes, stream);

    dim3 hgrid(chunks, TILES);
    ece_hist<<<hgrid, THREADS, 0, stream>>>(probs, N, C, R, partial);
    ece_cor<<<(N + 255) / 256, 256, 0, stream>>>(probs, labels, N, C, g_cor);
    dim3 r1grid((SLAB + 255) / 256, NGROUP);
    ece_red1<<<r1grid, 256, 0, stream>>>(partial, chunks, gsz, stage1);
    ece_red2<<<(C * NBINS + 255) / 256, 256, 0, stream>>>(stage1, g_cor, C, N, accum);
    ece_fin<<<1, 1, 0, stream>>>(accum, C, (float*)d_out);
}

// Round 4
// 143.458 us; speedup vs baseline: 6.1833x; 1.0324x over previous
//
#include <hip/hip_runtime.h>

// Classwise ECE, probs [N=100000, C=1000] f32, labels [N] i32 -> scalar f32.
// R4: count field dropped (|conf_sum - cor|/N identity), full-u32 q16 conf
// slots, stride-31 padded LDS (bank-conflict-free), label-gather fused into
// hist (tile-local, cache-hot), two-stage integer reduce (deterministic).

#define NBINS   15
#define THREADS 256
#define TC      512                 // classes per tile (2 per thread, float2)
#define TILES   2                   // covers C <= 1024
#define SLOTS   (TC * NBINS)        // 7680 logical slots per tile
#define PSTRIDE 31                  // padded per-thread LDS stride (odd!)
#define LDSW    (THREADS * PSTRIDE) // 7936 u32 = 31744 B -> 5 blocks/CU
#define SLAB    (TILES * SLOTS)     // 15360 u32 per chunk
#define NGROUP  16

__global__ __launch_bounds__(THREADS, 5) void ece_hist(
    const float* __restrict__ probs, const int* __restrict__ labels,
    int N, int C, int R,
    unsigned* __restrict__ partial,          // [chunks][SLAB] q16 conf sums
    unsigned* __restrict__ g_cor)            // [C*NBINS]
{
    __shared__ unsigned sA[LDSW];
    const int t = threadIdx.x;
    #pragma unroll
    for (int i = t; i < LDSW; i += THREADS) sA[i] = 0u;
    __syncthreads();

    const int chunk = blockIdx.x;
    const int tile  = blockIdx.y;
    const int cls0  = tile * TC + 2 * t;
    const int col   = (cls0 <= C - 2) ? cls0 : (C - 2);  // dead cols ignored later

    const int r0 = chunk * R;
    int rend = N - r0; if (rend > R) rend = R;

    const float2* p = (const float2*)(probs + (size_t)r0 * C + col);
    const size_t rowstep = (size_t)(C >> 1);
    unsigned* s0 = sA + t * PSTRIDE;         // bins: class0 [0,15), class1 [15,30)

    #pragma unroll 16
    for (int r = 0; r < rend; ++r) {
        float2 v = p[(size_t)r * rowstep];

        int b0 = (int)(v.x * 15.0f);         // trunc == floor (v>=0), == ref ceil-1
        b0 = b0 < NBINS - 1 ? b0 : NBINS - 1;
        unsigned c0 = (unsigned)fmaf(v.x, 65536.0f, 0.5f);
        atomicAdd(&s0[b0], (v.x > 0.0f) ? c0 : 0u);        // ds_add_u32, private

        int b1 = (int)(v.y * 15.0f);
        b1 = b1 < NBINS - 1 ? b1 : NBINS - 1;
        unsigned c1 = (unsigned)fmaf(v.y, 65536.0f, 0.5f);
        atomicAdd(&s0[NBINS + b1], (v.y > 0.0f) ? c1 : 0u);
    }

    // Fused correct-count: only labels inside this tile's class range; the
    // gathered addresses were just streamed by this block -> L1/L2 hot.
    for (int j = t; j < rend; j += THREADS) {
        int row = r0 + j;
        int lab = labels[row];
        int lc  = lab - tile * TC;
        if (lc >= 0 && lc < TC && lab < C) {
            float v = probs[(size_t)row * C + lab];
            if (v > 0.0f) {
                int b = (int)(v * 15.0f);
                b = b < NBINS - 1 ? b : NBINS - 1;
                atomicAdd(&g_cor[lab * NBINS + b], 1u);
            }
        }
    }
    __syncthreads();

    // Flush padded LDS -> linear class-major global (coalesced stores).
    unsigned* dst = partial + (size_t)chunk * SLAB + (size_t)tile * SLOTS;
    #pragma unroll
    for (int i = t; i < SLOTS; i += THREADS) {
        int owner = i / 30, j = i - owner * 30;       // slot i = class-major
        dst[i] = sA[owner * PSTRIDE + j];
    }
}

// Stage 1: per chunk-group conf partial sums (u32, exact).
__global__ __launch_bounds__(256) void ece_red1(
    const unsigned* __restrict__ partial, int chunks, int gsz,
    unsigned* __restrict__ stage1)           // [NGROUP][SLAB]
{
    int i = blockIdx.x * 256 + threadIdx.x;
    if (i >= SLAB) return;
    int g = blockIdx.y;
    int k0 = g * gsz;
    int k1 = k0 + gsz; if (k1 > chunks) k1 = chunks;
    unsigned conf = 0;
    #pragma unroll 8
    for (int k = k0; k < k1; ++k)
        conf += partial[(size_t)k * SLAB + i];
    stage1[(size_t)g * SLAB + i] = conf;
}

// Stage 2: contrib = |conf_sum - cor| / N  (count cancels; empty bins -> 0-0)
__global__ __launch_bounds__(256) void ece_red2(
    const unsigned* __restrict__ stage1, const unsigned* __restrict__ g_cor,
    int C, int N, unsigned long long* __restrict__ accum)
{
    int i = blockIdx.x * 256 + threadIdx.x;
    float contrib = 0.0f;
    if (i < C * NBINS) {
        unsigned long long conf = 0;
        #pragma unroll
        for (int g = 0; g < NGROUP; ++g)
            conf += stage1[(size_t)g * SLAB + i];
        float cf = (float)conf * (1.0f / 65536.0f);
        contrib = fabsf(cf - (float)g_cor[i]) * (1.0f / (float)N);
    }
    for (int o = 32; o; o >>= 1) contrib += __shfl_down(contrib, o);
    __shared__ float ws[4];
    const int wid = threadIdx.x >> 6, lane = threadIdx.x & 63;
    if (lane == 0) ws[wid] = contrib;
    __syncthreads();
    if (threadIdx.x == 0) {
        float s = ws[0] + ws[1] + ws[2] + ws[3];
        atomicAdd(accum, (unsigned long long)(s * 1099511627776.0f)); // q40
    }
}

__global__ void ece_fin(const unsigned long long* __restrict__ accum,
                        int C, float* __restrict__ out)
{
    out[0] = (float)((double)accum[0] * (1.0 / 1099511627776.0) / (double)C);
}

extern "C" void kernel_launch(void* const* d_in, const int* in_sizes, int n_in,
                              void* d_out, int out_size, void* d_ws, size_t ws_size,
                              hipStream_t stream) {
    const float* probs  = (const float*)d_in[0];
    const int*   labels = (const int*)d_in[1];
    const int N = in_sizes[1];              // 100000
    const int C = in_sizes[0] / N;          // 1000

    // ws: [accum u64][g_cor u32 x SLAB] pad 64K | stage1 u32[16][SLAB] | partials
    const size_t headBytes   = 65536;
    const size_t stage1Bytes = (size_t)NGROUP * SLAB * 4;   // 983 KB
    const size_t off_partial = headBytes + stage1Bytes;
    const size_t slabBytes   = (size_t)SLAB * 4;            // 61440

    unsigned long long* accum   = (unsigned long long*)d_ws;
    unsigned*           g_cor   = (unsigned*)((char*)d_ws + 8);
    unsigned*           stage1  = (unsigned*)((char*)d_ws + headBytes);
    unsigned*           partial = (unsigned*)((char*)d_ws + off_partial);

    long long avail = (long long)ws_size - (long long)off_partial;
    int chunks = (int)(avail / (long long)slabBytes);
    if (chunks > 640) chunks = 640;         // 640x2 tiles = 1280 blocks = 5/CU
    if (chunks < 2) chunks = 2;             // keeps R<=65535 (q16 sum fits u32)
    const int R = (N + chunks - 1) / chunks;
    const int gsz = (chunks + NGROUP - 1) / NGROUP;

    hipMemsetAsync(d_ws, 0, headBytes, stream);

    dim3 hgrid(chunks, TILES);
    ece_hist<<<hgrid, THREADS, 0, stream>>>(probs, labels, N, C, R, partial, g_cor);
    dim3 r1grid((SLAB + 255) / 256, NGROUP);
    ece_red1<<<r1grid, 256, 0, stream>>>(partial, chunks, gsz, stage1);
    ece_red2<<<(C * NBINS + 255) / 256, 256, 0, stream>>>(stage1, g_cor, C, N, accum);
    ece_fin<<<1, 1, 0, stream>>>(accum, C, (float*)d_out);
}